// Round 15
// baseline (246.563 us; speedup 1.0000x reference)
//
#include <hip/hip_runtime.h>
#include <hip/hip_bf16.h>
#include <hip/hip_fp16.h>
#include <math.h>

// ---------------------------------------------------------------------------
// QGINLayer, 7 dispatches, zero global atomics in CSR build, full-f16 pipeline:
//   initp1: hfrag build (f16) + statsR zero + per-chunk coarse hist
//   p2:     per-bucket scan over chunks -> PO, totals BT
//   p3:     per-chunk LDS-rank scatter -> tmp2 (col | f16val, row)
//   p4:     per-bucket LDS hist+scan -> row-grouped ew PADDED to 8 + (beg,cnt)
//   gemm1:  y(f16,ws) = x @ H1 [f16 MFMA, 64-row blocks, LDS-transpose epilogue]
//   spmm:   out1(f16, interleaved in d_out) = segsum(ev*y[col]) + BN stats
//           (1 row/wave, grid-stride 4, scalarized edge words, __hfma2 packed)
//   gemm2:  d_out(f32) = tanh(BN(out1)) @ H2 [f16 MFMA, NT stores]
// ---------------------------------------------------------------------------

#define FDIM 256
#define NREP 32     // replicated stat accumulators
#define CH 2048     // edges per chunk in binning

typedef __attribute__((ext_vector_type(8))) _Float16 f16x8;
typedef __attribute__((ext_vector_type(4))) float f32x4;

static __device__ inline ushort f2h_bits(float x) {
    _Float16 h = (_Float16)x;
    return __builtin_bit_cast(unsigned short, h);
}
static __device__ inline float h2f(ushort u) {
    return (float)__builtin_bit_cast(_Float16, u);
}
static __device__ inline float fast_tanh(float x) {
    float e = __expf(2.f * x);
    return 1.f - 2.f * __builtin_amdgcn_rcpf(e + 1.f);
}

// ---------- hamilton fragment builder (f16) ----------
static __device__ void build_hfrag(const float* __restrict__ w, ushort* __restrict__ hf,
                                   int t) {
    const int   comp_t[16] = {0,1,2,3,  1,0,3,2,  2,3,0,1,  3,2,1,0};
    const float sign_t[16] = {1,1,1,1, -1,1,1,-1, -1,-1,1,1, -1,1,-1,1};
    int f = t >> 6, lane = t & 63;
    int tile = f >> 3, kk = f & 7;
    int col = tile * 16 + (lane & 15);
    int b = col >> 6, q = col & 63;
    ushort o[8];
#pragma unroll
    for (int j = 0; j < 8; ++j) {
        int k = kk * 32 + ((lane >> 4) << 3) + j;
        int a = k >> 6, p = k & 63;
        int ab = a * 4 + b;
        float v = sign_t[ab] * w[p * 256 + comp_t[ab] * 64 + q];
        o[j] = f2h_bits(v);
    }
    *(ushort4*)(hf + (size_t)t * 8)     = make_ushort4(o[0], o[1], o[2], o[3]);
    *(ushort4*)(hf + (size_t)t * 8 + 4) = make_ushort4(o[4], o[5], o[6], o[7]);
}

// ---------- initp1: hfrag (0-63) + zero statsR (64-79) + coarse hist (80+) ----------
__global__ __launch_bounds__(256) void k_initp1(const float* __restrict__ w1,
                                                const float* __restrict__ w2,
                                                ushort* __restrict__ h1f,
                                                ushort* __restrict__ h2f,
                                                float* __restrict__ statsR,
                                                const int* __restrict__ rows,
                                                int* __restrict__ CM,
                                                int E, int nchunk, int NB) {
    int b = blockIdx.x;
    if (b < 32) {
        build_hfrag(w1, h1f, b * 256 + threadIdx.x);
        return;
    }
    if (b < 64) {
        build_hfrag(w2, h2f, (b - 32) * 256 + threadIdx.x);
        return;
    }
    if (b < 80) {
        int slot = (b - 64) * 256 + threadIdx.x;
        *(float4*)(statsR + slot * 4) = make_float4(0.f, 0.f, 0.f, 0.f);
        return;
    }
    __shared__ int lc[256];
    int t = threadIdx.x, c = b - 80;
    lc[t] = 0;
    __syncthreads();
#pragma unroll
    for (int i = 0; i < 8; ++i) {
        int e = c * CH + i * 256 + t;
        if (e < E) atomicAdd(&lc[rows[e] >> 9], 1);
    }
    __syncthreads();
    if (t < NB) CM[t * nchunk + c] = lc[t];
}

// ---------- P2: per-bucket exclusive scan over chunks ----------
__global__ __launch_bounds__(256) void k_p2(const int* __restrict__ CM,
                                            int* __restrict__ PO,
                                            int* __restrict__ BT, int nchunk) {
    __shared__ int ts[256];
    int t = threadIdx.x, b = blockIdx.x;
    int base = b * nchunk;
    int lex[4], s = 0;
#pragma unroll
    for (int i = 0; i < 4; ++i) {
        int c = t * 4 + i;
        int v = (c < nchunk) ? CM[base + c] : 0;
        lex[i] = s;
        s += v;
    }
    ts[t] = s;
    __syncthreads();
    for (int off = 1; off < 256; off <<= 1) {
        int v = (t >= off) ? ts[t - off] : 0;
        __syncthreads();
        ts[t] += v;
        __syncthreads();
    }
    int excl = ts[t] - s;
#pragma unroll
    for (int i = 0; i < 4; ++i) {
        int c = t * 4 + i;
        if (c < nchunk) PO[base + c] = excl + lex[i];
    }
    if (t == 255) BT[b] = ts[255];
}

// ---------- P3: per-chunk rank-scatter; value packed as f16 bits (15b) ----------
__global__ __launch_bounds__(256) void k_p3(const int* __restrict__ rows,
                                            const int* __restrict__ cols,
                                            const float* __restrict__ vals,
                                            const int* __restrict__ PO,
                                            const int* __restrict__ BT,
                                            uint2* __restrict__ tmp2,
                                            int E, int nchunk, int NB) {
    __shared__ int sBB[256];
    __shared__ int sPO[256];
    __shared__ int sLC[256];
    int t = threadIdx.x, c = blockIdx.x;
    int own = (t < NB) ? BT[t] : 0;
    sBB[t] = own;
    sPO[t] = (t < NB) ? PO[t * nchunk + c] : 0;
    sLC[t] = 0;
    __syncthreads();
    for (int off = 1; off < 256; off <<= 1) {
        int v = (t >= off) ? sBB[t - off] : 0;
        __syncthreads();
        sBB[t] += v;
        __syncthreads();
    }
    sBB[t] -= own;  // exclusive
    __syncthreads();
#pragma unroll
    for (int i = 0; i < 8; ++i) {
        int e = c * CH + i * 256 + t;
        if (e < E) {
            int r = rows[e];
            int b = r >> 9;
            int rank = atomicAdd(&sLC[b], 1);
            int pos = sBB[b] + sPO[b] + rank;
            unsigned int hv = f2h_bits(vals[e]);   // val in [0,1) -> bits < 0x3C00
            tmp2[pos] = make_uint2((unsigned int)cols[e] | (hv << 17),
                                   (unsigned int)r);
        }
    }
}

// ---------- P4: per-bucket row sort -> padded row-grouped ew + (beg,cnt) ----------
__global__ __launch_bounds__(1024) void k_p4(const uint2* __restrict__ tmp2,
                                             const int* __restrict__ BT,
                                             unsigned int* __restrict__ ew,
                                             uint2* __restrict__ offs2,
                                             int N, int NB) {
    __shared__ int sBB[256];
    __shared__ int sH[512];
    __shared__ int sHp[512];
    __shared__ int sOp[512];
    __shared__ int sC[512];
    int t = threadIdx.x, b = blockIdx.x;
    int own = 0;
    if (t < 256) {
        own = (t < NB) ? BT[t] : 0;
        sBB[t] = own;
    }
    __syncthreads();
    for (int off = 1; off < 256; off <<= 1) {
        int v = (t < 256 && t >= off) ? sBB[t - off] : 0;
        __syncthreads();
        if (t < 256) sBB[t] += v;
        __syncthreads();
    }
    if (t < 256) sBB[t] -= own;
    if (t < 512) sH[t] = 0;
    __syncthreads();
    const int base = sBB[b];
    const int basePad = sBB[b] + b * 4096;
    const int nE = BT[b];
    const int rbase = b << 9;
    for (int i = t; i < nE; i += 1024)
        atomicAdd(&sH[(int)tmp2[base + i].y - rbase], 1);
    __syncthreads();
    if (t < 512) {
        int hp = (sH[t] + 7) & ~7;
        sHp[t] = hp;
        sOp[t] = hp;
    }
    __syncthreads();
    for (int off = 1; off < 512; off <<= 1) {
        int v = (t < 512 && t >= off) ? sOp[t - off] : 0;
        __syncthreads();
        if (t < 512) sOp[t] += v;
        __syncthreads();
    }
    if (t < 512) {
        sOp[t] -= sHp[t];
        int r = rbase + t;
        if (r < N) offs2[r] = make_uint2((unsigned int)(basePad + sOp[t]),
                                         (unsigned int)sHp[t]);
        sC[t] = 0;
    }
    __syncthreads();
    for (int i = t; i < nE; i += 1024) {
        uint2 u = tmp2[base + i];
        int lr = (int)u.y - rbase;
        int p = atomicAdd(&sC[lr], 1);
        ew[basePad + sOp[lr] + p] = u.x;
    }
    if (t < 512) {
        int e0 = basePad + sOp[t] + sH[t];
        int e1 = basePad + sOp[t] + sHp[t];
        for (int e = e0; e < e1; ++e) ew[e] = 0u;
    }
}

// ---------- GEMM1: y(f16) = x(f32) @ H1f ; 64-row blocks ----------
__global__ __launch_bounds__(256) void k_gemm1(const float* __restrict__ X,
                                               const ushort* __restrict__ Bf,
                                               ushort* __restrict__ Y, int N) {
    __shared__ float4 lds4[2048];   // 32 KB
    ushort* lds = (ushort*)lds4;
    const int t = threadIdx.x;
    const int w = t >> 6, lane = t & 63;
    const int r0 = blockIdx.x * 64 + w * 16;
    const int q = (lane >> 4) & 3, l = lane & 15;
    const int kbase = q * 8;
    const int rA = min(r0 + l, N - 1);

    f16x8 af[8];
#pragma unroll
    for (int kk = 0; kk < 8; ++kk) {
        const float* p = X + (size_t)rA * 256 + kk * 32 + kbase;
        float4 v0 = *(const float4*)p;
        float4 v1 = *(const float4*)(p + 4);
        f16x8 a;
        a[0] = (_Float16)v0.x; a[1] = (_Float16)v0.y;
        a[2] = (_Float16)v0.z; a[3] = (_Float16)v0.w;
        a[4] = (_Float16)v1.x; a[5] = (_Float16)v1.y;
        a[6] = (_Float16)v1.z; a[7] = (_Float16)v1.w;
        af[kk] = a;
    }

    for (int g = 0; g < 4; ++g) {
        {   // stage B group (conflict-free mapping)
            const float4* s4 = (const float4*)(Bf + (size_t)g * 16384);
#pragma unroll
            for (int i = 0; i < 8; ++i) lds4[i * 256 + t] = s4[i * 256 + t];
        }
        __syncthreads();

        f32x4 acc[4];
#pragma unroll
        for (int tg = 0; tg < 4; ++tg) acc[tg] = (f32x4){0.f, 0.f, 0.f, 0.f};

#pragma unroll
        for (int tg = 0; tg < 4; ++tg)
#pragma unroll
            for (int kk = 0; kk < 8; ++kk) {
                f16x8 b = *(const f16x8*)(lds + ((tg * 8 + kk) * 64 + lane) * 8);
                acc[tg] = __builtin_amdgcn_mfma_f32_16x16x32_f16(af[kk], b, acc[tg], 0, 0, 0);
            }
        __syncthreads();  // all waves done reading B before epilogue reuses lds

        // epilogue: acc -> LDS (wave-local 2KB region) -> 16B stores
        {
            ushort* cw = lds + w * 1024;
#pragma unroll
            for (int tg = 0; tg < 4; ++tg)
#pragma unroll
                for (int j = 0; j < 4; ++j)
                    cw[(q * 4 + j) * 64 + tg * 16 + l] = f2h_bits(acc[tg][j]);
        }
        __syncthreads();
        {
            int gcol0 = g * 64;
#pragma unroll
            for (int p = 0; p < 2; ++p) {
                uint4 rd = *(const uint4*)(lds + w * 1024 + p * 512 + lane * 8);
                int row = r0 + p * 8 + (lane >> 3);
                int col = gcol0 + (lane & 7) * 8;
                if (row < N) *(uint4*)(Y + (size_t)row * 256 + col) = rd;
            }
        }
        __syncthreads();
    }
}

// ---------- SpMM (full pass): 1 row/wave, grid-stride 4, packed f16 MAC ----------
__global__ __launch_bounds__(256) void k_spmm(const ushort* __restrict__ Y,
                                              const uint2* __restrict__ offs2,
                                              const unsigned int* __restrict__ ew,
                                              ushort* __restrict__ O,
                                              float* __restrict__ statsR,
                                              int n, int W) {
    __shared__ float ls_s[4][256];
    __shared__ float ls_q[4][256];
    const int tid = threadIdx.x;
    const int w = tid >> 6, lane = tid & 63;
    const int gw = blockIdx.x * 4 + w;

    float s0 = 0.f, s1 = 0.f, s2 = 0.f, s3 = 0.f;
    float q0 = 0.f, q1 = 0.f, q2 = 0.f, q3 = 0.f;

    for (int k = 0; k < 4; ++k) {
        int row = gw + k * W;
        bool ok = row < n;
        int r = ok ? row : 0;
        uint2 bc = offs2[r];
        int cnt = ok ? (int)bc.y : 0;   // padded, multiple of 8
        int g = cnt >> 3;
        const unsigned int* ep = ew + bc.x;

        __half2 a01 = __builtin_bit_cast(__half2, 0u);
        __half2 a23 = __builtin_bit_cast(__half2, 0u);
        unsigned int wv[8];
        if (g > 0) {
#pragma unroll
            for (int i = 0; i < 8; ++i) wv[i] = ep[i];
        }
        for (int gi = 0; gi < g; ++gi) {
            unsigned int wn[8];
            bool more = (gi + 1) < g;
            if (more) {
#pragma unroll
                for (int i = 0; i < 8; ++i) wn[i] = ep[(gi + 1) * 8 + i];
            }
#pragma unroll
            for (int i = 0; i < 8; ++i) {
                unsigned int wd = (unsigned int)__builtin_amdgcn_readfirstlane((int)wv[i]);
                unsigned int c = wd & 0x1FFFFu;
                unsigned int hv = wd >> 17;          // f16 bits of val (pad -> 0)
                __half2 vv = __builtin_bit_cast(__half2, hv | (hv << 16));
                uint2 u = *(const uint2*)(Y + (size_t)c * 256 + lane * 4);
                a01 = __hfma2(__builtin_bit_cast(__half2, u.x), vv, a01);
                a23 = __hfma2(__builtin_bit_cast(__half2, u.y), vv, a23);
            }
            if (more) {
#pragma unroll
                for (int i = 0; i < 8; ++i) wv[i] = wn[i];
            }
        }
        if (ok) {
            uint2 o = make_uint2(__builtin_bit_cast(unsigned int, a01),
                                 __builtin_bit_cast(unsigned int, a23));
            *(uint2*)(O + (size_t)r * 512 + lane * 4) = o;
        }
        float2 f01 = __half22float2(a01);
        float2 f23 = __half22float2(a23);
        s0 += f01.x; q0 = fmaf(f01.x, f01.x, q0);
        s1 += f01.y; q1 = fmaf(f01.y, f01.y, q1);
        s2 += f23.x; q2 = fmaf(f23.x, f23.x, q2);
        s3 += f23.y; q3 = fmaf(f23.y, f23.y, q3);
    }

    // ---- fused BN stats: one LDS round + replicated global atomics ----
    int rep = blockIdx.x & (NREP - 1);
    *(float4*)&ls_s[w][lane * 4] = make_float4(s0, s1, s2, s3);
    *(float4*)&ls_q[w][lane * 4] = make_float4(q0, q1, q2, q3);
    __syncthreads();
    float sv = ls_s[0][tid] + ls_s[1][tid] + ls_s[2][tid] + ls_s[3][tid];
    float qv = ls_q[0][tid] + ls_q[1][tid] + ls_q[2][tid] + ls_q[3][tid];
    atomicAdd(&statsR[rep * 256 + tid], sv);
    atomicAdd(&statsR[NREP * 256 + rep * 256 + tid], qv);
}

// ---------- GEMM2: d_out(f32,in-place) = tanh(BN(out1)) @ H2f ; NT stores ----------
__global__ __launch_bounds__(256) void k_gemm2(void* __restrict__ Av,
                                               const ushort* __restrict__ Bf,
                                               const float* __restrict__ statsR,
                                               const float* __restrict__ gamma,
                                               const float* __restrict__ beta, int N) {
    __shared__ float4 lds4[2048];   // 32 KB
    ushort* lds = (ushort*)lds4;
    __shared__ float sscl[256], sshf[256];
    const int t = threadIdx.x;
    const int w = t >> 6, lane = t & 63;
    const int r0 = blockIdx.x * 64 + w * 16;
    const int q = (lane >> 4) & 3, l = lane & 15;
    const int kbase = q * 8;
    const int rA = min(r0 + l, N - 1);

    {   // fused bnfinal
        float s = 0.f, qq = 0.f;
#pragma unroll
        for (int i = 0; i < NREP; ++i) {
            s += statsR[i * 256 + t];
            qq += statsR[NREP * 256 + i * 256 + t];
        }
        float invn = 1.0f / (float)N;
        float mean = s * invn;
        float var = qq * invn - mean * mean;
        float inv = rsqrtf(var + 1e-5f);
        float gg = gamma[t] * inv;
        sscl[t] = gg;
        sshf[t] = beta[t] - mean * gg;
        __syncthreads();
    }

    const ushort* X = (const ushort*)Av;
    f16x8 af[8];
#pragma unroll
    for (int kk = 0; kk < 8; ++kk) {
        const ushort* p = X + (size_t)rA * 512 + kk * 32 + kbase;
        ushort4 u0 = *(const ushort4*)p;
        ushort4 u1 = *(const ushort4*)(p + 4);
        float4 s0 = *(const float4*)&sscl[kk * 32 + kbase];
        float4 s1 = *(const float4*)&sscl[kk * 32 + kbase + 4];
        float4 h0 = *(const float4*)&sshf[kk * 32 + kbase];
        float4 h1 = *(const float4*)&sshf[kk * 32 + kbase + 4];
        f16x8 a;
        a[0] = (_Float16)fast_tanh(fmaf(h2f(u0.x), s0.x, h0.x));
        a[1] = (_Float16)fast_tanh(fmaf(h2f(u0.y), s0.y, h0.y));
        a[2] = (_Float16)fast_tanh(fmaf(h2f(u0.z), s0.z, h0.z));
        a[3] = (_Float16)fast_tanh(fmaf(h2f(u0.w), s0.w, h0.w));
        a[4] = (_Float16)fast_tanh(fmaf(h2f(u1.x), s1.x, h1.x));
        a[5] = (_Float16)fast_tanh(fmaf(h2f(u1.y), s1.y, h1.y));
        a[6] = (_Float16)fast_tanh(fmaf(h2f(u1.z), s1.z, h1.z));
        a[7] = (_Float16)fast_tanh(fmaf(h2f(u1.w), s1.w, h1.w));
        af[kk] = a;
    }

    float* Cf = (float*)Av;
    for (int g = 0; g < 4; ++g) {
        {   // stage B group (conflict-free mapping)
            const float4* s4 = (const float4*)(Bf + (size_t)g * 16384);
#pragma unroll
            for (int i = 0; i < 8; ++i) lds4[i * 256 + t] = s4[i * 256 + t];
        }
        __syncthreads();  // also drains A-loads before in-place stores below

        f32x4 acc[4];
#pragma unroll
        for (int tg = 0; tg < 4; ++tg) acc[tg] = (f32x4){0.f, 0.f, 0.f, 0.f};

#pragma unroll
        for (int tg = 0; tg < 4; ++tg)
#pragma unroll
            for (int kk = 0; kk < 8; ++kk) {
                f16x8 b = *(const f16x8*)(lds + ((tg * 8 + kk) * 64 + lane) * 8);
                acc[tg] = __builtin_amdgcn_mfma_f32_16x16x32_f16(af[kk], b, acc[tg], 0, 0, 0);
            }
        __syncthreads();  // all waves done reading B before epilogue reuses lds

        // epilogue: acc -> LDS (wave-local 4KB f32 region) -> 16B NT stores
        {
            float* cw = (float*)lds4 + w * 1024;
#pragma unroll
            for (int tg = 0; tg < 4; ++tg)
#pragma unroll
                for (int j = 0; j < 4; ++j)
                    cw[(q * 4 + j) * 64 + tg * 16 + l] = acc[tg][j];
        }
        __syncthreads();
        {
            int gcol0 = g * 64;
#pragma unroll
            for (int p = 0; p < 4; ++p) {
                f32x4 rd = *(const f32x4*)((float*)lds4 + w * 1024 + p * 256 + lane * 4);
                int row = r0 + p * 4 + (lane >> 4);
                int col = gcol0 + (lane & 15) * 4;
                if (row < N)
                    __builtin_nontemporal_store(rd, (f32x4*)(Cf + (size_t)row * 256 + col));
            }
        }
        __syncthreads();
    }
}

extern "C" void kernel_launch(void* const* d_in, const int* in_sizes, int n_in,
                              void* d_out, int out_size, void* d_ws, size_t ws_size,
                              hipStream_t stream) {
    const float* x     = (const float*)d_in[0];
    const int* rows    = (const int*)d_in[1];
    const int* cols    = (const int*)d_in[2];
    const float* evin  = (const float*)d_in[3];
    const float* w1    = (const float*)d_in[4];
    const float* w2    = (const float*)d_in[5];
    const float* gamma = (const float*)d_in[6];
    const float* beta  = (const float*)d_in[7];
    float* out = (float*)d_out;

    const int N = in_sizes[0] / FDIM;       // 100000
    const int E = in_sizes[1];              // 1600000
    const int NB = (N + 511) >> 9;          // 196 coarse buckets
    const int nchunk = (E + CH - 1) / CH;   // 782

    char* ws = (char*)d_ws;
    size_t o = 0;
    auto alloc = [&](size_t bytes) -> char* {
        char* p = ws + o;
        o += (bytes + 255) & ~(size_t)255;
        return p;
    };
    ushort* h1f  = (ushort*)alloc(128 * 64 * 8 * 2);
    ushort* h2f  = (ushort*)alloc(128 * 64 * 8 * 2);
    ushort* y    = (ushort*)alloc((size_t)N * 256 * 2);             // 51.2 MB
    float* statsR = (float*)alloc(2 * NREP * 256 * 4);              // 64 KB
    int*   CM    = (int*)alloc((size_t)NB * nchunk * 4);            // 612 KB
    int*   PO    = (int*)alloc((size_t)NB * nchunk * 4);            // 612 KB
    int*   BT    = (int*)alloc(256 * 4);
    uint2* tmp2  = (uint2*)alloc((size_t)E * 8);                    // 12.8 MB
    unsigned int* ewp = (unsigned int*)alloc(((size_t)E + (size_t)NB * 4096 + 16) * 4);
    uint2* offs2 = (uint2*)alloc((size_t)N * 8);                    // 800 KB

    // init + p1 in one dispatch
    k_initp1<<<80 + nchunk, 256, 0, stream>>>(w1, w2, h1f, h2f, statsR,
                                              rows, CM, E, nchunk, NB);
    k_p2<<<NB, 256, 0, stream>>>(CM, PO, BT, nchunk);
    k_p3<<<nchunk, 256, 0, stream>>>(rows, cols, evin, PO, BT, tmp2, E, nchunk, NB);
    k_p4<<<NB, 1024, 0, stream>>>(tmp2, BT, ewp, offs2, N, NB);

    int gblk = (N + 63) / 64;  // 1563
    // y = x @ H1 (f16)
    k_gemm1<<<gblk, 256, 0, stream>>>(x, h1f, y, N);
    // out1(f16, interleaved in d_out) = segsum(ev * y[col]) + BN stats
    int W = (N + 3) / 4;
    int sblk = (W + 3) / 4;
    k_spmm<<<sblk, 256, 0, stream>>>(y, offs2, ewp, (ushort*)out, statsR, N, W);
    // d_out(f32) = tanh(BN(out1)) @ H2
    k_gemm2<<<gblk, 256, 0, stream>>>(out, h2f, statsR, gamma, beta, N);
}

// Round 16
// 241.702 us; speedup vs baseline: 1.0201x; 1.0201x over previous
//
#include <hip/hip_runtime.h>
#include <hip/hip_bf16.h>
#include <hip/hip_fp16.h>
#include <math.h>

// ---------------------------------------------------------------------------
// QGINLayer, 7 dispatches, zero global atomics in CSR build, full-f16 pipeline:
//   initp1: hfrag build (f16) + statsR zero + per-chunk coarse hist
//   p2:     per-bucket scan over chunks -> PO, totals BT
//   p3:     per-chunk LDS-rank scatter -> tmp2 (col | f16val, row)
//   p4:     per-bucket LDS hist+scan -> row-grouped ew PADDED to 8 + (beg,cnt)
//   gemm1:  y(f16,ws) = x @ H1 [f16 MFMA, 64-row blocks, LDS-transpose epilogue]
//   spmm:   out1(f16, interleaved in d_out) = segsum(ev*y[col]) + BN stats
//           XCD-PARTITIONED feature halves: blockIdx%8 -> {feature half, row stripe}
//           so each XCD's L2 only ever sees 25.6 MB of y (FETCH 378->~205 MB)
//   gemm2:  d_out(f32) = tanh(BN(out1)) @ H2 [f16 MFMA, NT stores]
// ---------------------------------------------------------------------------

#define FDIM 256
#define NREP 32     // replicated stat accumulators
#define CH 2048     // edges per chunk in binning

typedef __attribute__((ext_vector_type(8))) _Float16 f16x8;
typedef __attribute__((ext_vector_type(4))) float f32x4;

static __device__ inline ushort f2h_bits(float x) {
    _Float16 h = (_Float16)x;
    return __builtin_bit_cast(unsigned short, h);
}
static __device__ inline float h2f(ushort u) {
    return (float)__builtin_bit_cast(_Float16, u);
}
static __device__ inline float fast_tanh(float x) {
    float e = __expf(2.f * x);
    return 1.f - 2.f * __builtin_amdgcn_rcpf(e + 1.f);
}

// ---------- hamilton fragment builder (f16) ----------
static __device__ void build_hfrag(const float* __restrict__ w, ushort* __restrict__ hf,
                                   int t) {
    const int   comp_t[16] = {0,1,2,3,  1,0,3,2,  2,3,0,1,  3,2,1,0};
    const float sign_t[16] = {1,1,1,1, -1,1,1,-1, -1,-1,1,1, -1,1,-1,1};
    int f = t >> 6, lane = t & 63;
    int tile = f >> 3, kk = f & 7;
    int col = tile * 16 + (lane & 15);
    int b = col >> 6, q = col & 63;
    ushort o[8];
#pragma unroll
    for (int j = 0; j < 8; ++j) {
        int k = kk * 32 + ((lane >> 4) << 3) + j;
        int a = k >> 6, p = k & 63;
        int ab = a * 4 + b;
        float v = sign_t[ab] * w[p * 256 + comp_t[ab] * 64 + q];
        o[j] = f2h_bits(v);
    }
    *(ushort4*)(hf + (size_t)t * 8)     = make_ushort4(o[0], o[1], o[2], o[3]);
    *(ushort4*)(hf + (size_t)t * 8 + 4) = make_ushort4(o[4], o[5], o[6], o[7]);
}

// ---------- initp1: hfrag (0-63) + zero statsR (64-79) + coarse hist (80+) ----------
__global__ __launch_bounds__(256) void k_initp1(const float* __restrict__ w1,
                                                const float* __restrict__ w2,
                                                ushort* __restrict__ h1f,
                                                ushort* __restrict__ h2f,
                                                float* __restrict__ statsR,
                                                const int* __restrict__ rows,
                                                int* __restrict__ CM,
                                                int E, int nchunk, int NB) {
    int b = blockIdx.x;
    if (b < 32) {
        build_hfrag(w1, h1f, b * 256 + threadIdx.x);
        return;
    }
    if (b < 64) {
        build_hfrag(w2, h2f, (b - 32) * 256 + threadIdx.x);
        return;
    }
    if (b < 80) {
        int slot = (b - 64) * 256 + threadIdx.x;
        *(float4*)(statsR + slot * 4) = make_float4(0.f, 0.f, 0.f, 0.f);
        return;
    }
    __shared__ int lc[256];
    int t = threadIdx.x, c = b - 80;
    lc[t] = 0;
    __syncthreads();
#pragma unroll
    for (int i = 0; i < 8; ++i) {
        int e = c * CH + i * 256 + t;
        if (e < E) atomicAdd(&lc[rows[e] >> 9], 1);
    }
    __syncthreads();
    if (t < NB) CM[t * nchunk + c] = lc[t];
}

// ---------- P2: per-bucket exclusive scan over chunks ----------
__global__ __launch_bounds__(256) void k_p2(const int* __restrict__ CM,
                                            int* __restrict__ PO,
                                            int* __restrict__ BT, int nchunk) {
    __shared__ int ts[256];
    int t = threadIdx.x, b = blockIdx.x;
    int base = b * nchunk;
    int lex[4], s = 0;
#pragma unroll
    for (int i = 0; i < 4; ++i) {
        int c = t * 4 + i;
        int v = (c < nchunk) ? CM[base + c] : 0;
        lex[i] = s;
        s += v;
    }
    ts[t] = s;
    __syncthreads();
    for (int off = 1; off < 256; off <<= 1) {
        int v = (t >= off) ? ts[t - off] : 0;
        __syncthreads();
        ts[t] += v;
        __syncthreads();
    }
    int excl = ts[t] - s;
#pragma unroll
    for (int i = 0; i < 4; ++i) {
        int c = t * 4 + i;
        if (c < nchunk) PO[base + c] = excl + lex[i];
    }
    if (t == 255) BT[b] = ts[255];
}

// ---------- P3: per-chunk rank-scatter; value packed as f16 bits (15b) ----------
__global__ __launch_bounds__(256) void k_p3(const int* __restrict__ rows,
                                            const int* __restrict__ cols,
                                            const float* __restrict__ vals,
                                            const int* __restrict__ PO,
                                            const int* __restrict__ BT,
                                            uint2* __restrict__ tmp2,
                                            int E, int nchunk, int NB) {
    __shared__ int sBB[256];
    __shared__ int sPO[256];
    __shared__ int sLC[256];
    int t = threadIdx.x, c = blockIdx.x;
    int own = (t < NB) ? BT[t] : 0;
    sBB[t] = own;
    sPO[t] = (t < NB) ? PO[t * nchunk + c] : 0;
    sLC[t] = 0;
    __syncthreads();
    for (int off = 1; off < 256; off <<= 1) {
        int v = (t >= off) ? sBB[t - off] : 0;
        __syncthreads();
        sBB[t] += v;
        __syncthreads();
    }
    sBB[t] -= own;  // exclusive
    __syncthreads();
#pragma unroll
    for (int i = 0; i < 8; ++i) {
        int e = c * CH + i * 256 + t;
        if (e < E) {
            int r = rows[e];
            int b = r >> 9;
            int rank = atomicAdd(&sLC[b], 1);
            int pos = sBB[b] + sPO[b] + rank;
            unsigned int hv = f2h_bits(vals[e]);   // val in [0,1) -> bits < 0x3C00
            tmp2[pos] = make_uint2((unsigned int)cols[e] | (hv << 17),
                                   (unsigned int)r);
        }
    }
}

// ---------- P4: per-bucket row sort -> padded row-grouped ew + (beg,cnt) ----------
__global__ __launch_bounds__(1024) void k_p4(const uint2* __restrict__ tmp2,
                                             const int* __restrict__ BT,
                                             unsigned int* __restrict__ ew,
                                             uint2* __restrict__ offs2,
                                             int N, int NB) {
    __shared__ int sBB[256];
    __shared__ int sH[512];
    __shared__ int sHp[512];
    __shared__ int sOp[512];
    __shared__ int sC[512];
    int t = threadIdx.x, b = blockIdx.x;
    int own = 0;
    if (t < 256) {
        own = (t < NB) ? BT[t] : 0;
        sBB[t] = own;
    }
    __syncthreads();
    for (int off = 1; off < 256; off <<= 1) {
        int v = (t < 256 && t >= off) ? sBB[t - off] : 0;
        __syncthreads();
        if (t < 256) sBB[t] += v;
        __syncthreads();
    }
    if (t < 256) sBB[t] -= own;
    if (t < 512) sH[t] = 0;
    __syncthreads();
    const int base = sBB[b];
    const int basePad = sBB[b] + b * 4096;
    const int nE = BT[b];
    const int rbase = b << 9;
    for (int i = t; i < nE; i += 1024)
        atomicAdd(&sH[(int)tmp2[base + i].y - rbase], 1);
    __syncthreads();
    if (t < 512) {
        int hp = (sH[t] + 7) & ~7;
        sHp[t] = hp;
        sOp[t] = hp;
    }
    __syncthreads();
    for (int off = 1; off < 512; off <<= 1) {
        int v = (t < 512 && t >= off) ? sOp[t - off] : 0;
        __syncthreads();
        if (t < 512) sOp[t] += v;
        __syncthreads();
    }
    if (t < 512) {
        sOp[t] -= sHp[t];
        int r = rbase + t;
        if (r < N) offs2[r] = make_uint2((unsigned int)(basePad + sOp[t]),
                                         (unsigned int)sHp[t]);
        sC[t] = 0;
    }
    __syncthreads();
    for (int i = t; i < nE; i += 1024) {
        uint2 u = tmp2[base + i];
        int lr = (int)u.y - rbase;
        int p = atomicAdd(&sC[lr], 1);
        ew[basePad + sOp[lr] + p] = u.x;
    }
    if (t < 512) {
        int e0 = basePad + sOp[t] + sH[t];
        int e1 = basePad + sOp[t] + sHp[t];
        for (int e = e0; e < e1; ++e) ew[e] = 0u;
    }
}

// ---------- GEMM1: y(f16) = x(f32) @ H1f ; 64-row blocks ----------
__global__ __launch_bounds__(256) void k_gemm1(const float* __restrict__ X,
                                               const ushort* __restrict__ Bf,
                                               ushort* __restrict__ Y, int N) {
    __shared__ float4 lds4[2048];   // 32 KB
    ushort* lds = (ushort*)lds4;
    const int t = threadIdx.x;
    const int w = t >> 6, lane = t & 63;
    const int r0 = blockIdx.x * 64 + w * 16;
    const int q = (lane >> 4) & 3, l = lane & 15;
    const int kbase = q * 8;
    const int rA = min(r0 + l, N - 1);

    f16x8 af[8];
#pragma unroll
    for (int kk = 0; kk < 8; ++kk) {
        const float* p = X + (size_t)rA * 256 + kk * 32 + kbase;
        float4 v0 = *(const float4*)p;
        float4 v1 = *(const float4*)(p + 4);
        f16x8 a;
        a[0] = (_Float16)v0.x; a[1] = (_Float16)v0.y;
        a[2] = (_Float16)v0.z; a[3] = (_Float16)v0.w;
        a[4] = (_Float16)v1.x; a[5] = (_Float16)v1.y;
        a[6] = (_Float16)v1.z; a[7] = (_Float16)v1.w;
        af[kk] = a;
    }

    for (int g = 0; g < 4; ++g) {
        {   // stage B group (conflict-free mapping)
            const float4* s4 = (const float4*)(Bf + (size_t)g * 16384);
#pragma unroll
            for (int i = 0; i < 8; ++i) lds4[i * 256 + t] = s4[i * 256 + t];
        }
        __syncthreads();

        f32x4 acc[4];
#pragma unroll
        for (int tg = 0; tg < 4; ++tg) acc[tg] = (f32x4){0.f, 0.f, 0.f, 0.f};

#pragma unroll
        for (int tg = 0; tg < 4; ++tg)
#pragma unroll
            for (int kk = 0; kk < 8; ++kk) {
                f16x8 b = *(const f16x8*)(lds + ((tg * 8 + kk) * 64 + lane) * 8);
                acc[tg] = __builtin_amdgcn_mfma_f32_16x16x32_f16(af[kk], b, acc[tg], 0, 0, 0);
            }
        __syncthreads();  // all waves done reading B before epilogue reuses lds

        // epilogue: acc -> LDS (wave-local 2KB region) -> 16B stores
        {
            ushort* cw = lds + w * 1024;
#pragma unroll
            for (int tg = 0; tg < 4; ++tg)
#pragma unroll
                for (int j = 0; j < 4; ++j)
                    cw[(q * 4 + j) * 64 + tg * 16 + l] = f2h_bits(acc[tg][j]);
        }
        __syncthreads();
        {
            int gcol0 = g * 64;
#pragma unroll
            for (int p = 0; p < 2; ++p) {
                uint4 rd = *(const uint4*)(lds + w * 1024 + p * 512 + lane * 8);
                int row = r0 + p * 8 + (lane >> 3);
                int col = gcol0 + (lane & 7) * 8;
                if (row < N) *(uint4*)(Y + (size_t)row * 256 + col) = rd;
            }
        }
        __syncthreads();
    }
}

// ---------- SpMM: XCD-partitioned feature halves + row stripes ----------
// slot = blockIdx%8 -> XCD (round-robin heuristic). half = slot>>2 (features),
// stripe = slot&3 (row-blocks). Each XCD touches only 25.6 MB of y.
__global__ __launch_bounds__(256) void k_spmm(const ushort* __restrict__ Y,
                                              const uint2* __restrict__ offs2,
                                              const unsigned int* __restrict__ ew,
                                              ushort* __restrict__ O,
                                              float* __restrict__ statsR, int n) {
    __shared__ float ls_s[4][128];
    __shared__ float ls_q[4][128];
    const int tid = threadIdx.x;
    const int w = tid >> 6, lane = tid & 63;
    const int slot = blockIdx.x & 7;
    const int rbg  = blockIdx.x >> 3;
    const int half = slot >> 2;
    const int rb   = rbg * 4 + (slot & 3);   // row-block of 16 rows
    const int fb   = half * 128 + lane * 2;  // 2 features per lane

    float s0 = 0.f, s1 = 0.f, q0 = 0.f, q1 = 0.f;

    for (int k = 0; k < 4; ++k) {
        int row = rb * 16 + w * 4 + k;
        bool ok = row < n;
        int r = ok ? row : 0;
        uint2 bc = offs2[r];
        int cnt = ok ? (int)bc.y : 0;   // padded, multiple of 8
        int g = cnt >> 3;
        const unsigned int* ep = ew + bc.x;

        __half2 acc = __builtin_bit_cast(__half2, 0u);
        unsigned int wv[8];
        if (g > 0) {
#pragma unroll
            for (int i = 0; i < 8; ++i) wv[i] = ep[i];
        }
        for (int gi = 0; gi < g; ++gi) {
            unsigned int wn[8];
            bool more = (gi + 1) < g;
            if (more) {
#pragma unroll
                for (int i = 0; i < 8; ++i) wn[i] = ep[(gi + 1) * 8 + i];
            }
#pragma unroll
            for (int i = 0; i < 8; ++i) {
                unsigned int wd = (unsigned int)__builtin_amdgcn_readfirstlane((int)wv[i]);
                unsigned int c = wd & 0x1FFFFu;
                unsigned int hv = wd >> 17;          // f16 bits of val (pad -> 0)
                __half2 vv = __builtin_bit_cast(__half2, hv | (hv << 16));
                unsigned int u = *(const unsigned int*)(Y + (size_t)c * 256 + fb);
                acc = __hfma2(__builtin_bit_cast(__half2, u), vv, acc);
            }
            if (more) {
#pragma unroll
                for (int i = 0; i < 8; ++i) wv[i] = wn[i];
            }
        }
        if (ok) {
            *(unsigned int*)(O + (size_t)r * 512 + fb) =
                __builtin_bit_cast(unsigned int, acc);
        }
        float2 f01 = __half22float2(acc);
        s0 += f01.x; q0 = fmaf(f01.x, f01.x, q0);
        s1 += f01.y; q1 = fmaf(f01.y, f01.y, q1);
    }

    // ---- fused BN stats (this half's 128 features) ----
    int rep = rbg & (NREP - 1);
    *(float2*)&ls_s[w][lane * 2] = make_float2(s0, s1);
    *(float2*)&ls_q[w][lane * 2] = make_float2(q0, q1);
    __syncthreads();
    if (tid < 128) {
        float sv = ls_s[0][tid] + ls_s[1][tid] + ls_s[2][tid] + ls_s[3][tid];
        float qv = ls_q[0][tid] + ls_q[1][tid] + ls_q[2][tid] + ls_q[3][tid];
        atomicAdd(&statsR[rep * 256 + half * 128 + tid], sv);
        atomicAdd(&statsR[NREP * 256 + rep * 256 + half * 128 + tid], qv);
    }
}

// ---------- GEMM2: d_out(f32,in-place) = tanh(BN(out1)) @ H2f ; NT stores ----------
__global__ __launch_bounds__(256) void k_gemm2(void* __restrict__ Av,
                                               const ushort* __restrict__ Bf,
                                               const float* __restrict__ statsR,
                                               const float* __restrict__ gamma,
                                               const float* __restrict__ beta, int N) {
    __shared__ float4 lds4[2048];   // 32 KB
    ushort* lds = (ushort*)lds4;
    __shared__ float sscl[256], sshf[256];
    const int t = threadIdx.x;
    const int w = t >> 6, lane = t & 63;
    const int r0 = blockIdx.x * 64 + w * 16;
    const int q = (lane >> 4) & 3, l = lane & 15;
    const int kbase = q * 8;
    const int rA = min(r0 + l, N - 1);

    {   // fused bnfinal
        float s = 0.f, qq = 0.f;
#pragma unroll
        for (int i = 0; i < NREP; ++i) {
            s += statsR[i * 256 + t];
            qq += statsR[NREP * 256 + i * 256 + t];
        }
        float invn = 1.0f / (float)N;
        float mean = s * invn;
        float var = qq * invn - mean * mean;
        float inv = rsqrtf(var + 1e-5f);
        float gg = gamma[t] * inv;
        sscl[t] = gg;
        sshf[t] = beta[t] - mean * gg;
        __syncthreads();
    }

    const ushort* X = (const ushort*)Av;
    f16x8 af[8];
#pragma unroll
    for (int kk = 0; kk < 8; ++kk) {
        const ushort* p = X + (size_t)rA * 512 + kk * 32 + kbase;
        ushort4 u0 = *(const ushort4*)p;
        ushort4 u1 = *(const ushort4*)(p + 4);
        float4 s0 = *(const float4*)&sscl[kk * 32 + kbase];
        float4 s1 = *(const float4*)&sscl[kk * 32 + kbase + 4];
        float4 h0 = *(const float4*)&sshf[kk * 32 + kbase];
        float4 h1 = *(const float4*)&sshf[kk * 32 + kbase + 4];
        f16x8 a;
        a[0] = (_Float16)fast_tanh(fmaf(h2f(u0.x), s0.x, h0.x));
        a[1] = (_Float16)fast_tanh(fmaf(h2f(u0.y), s0.y, h0.y));
        a[2] = (_Float16)fast_tanh(fmaf(h2f(u0.z), s0.z, h0.z));
        a[3] = (_Float16)fast_tanh(fmaf(h2f(u0.w), s0.w, h0.w));
        a[4] = (_Float16)fast_tanh(fmaf(h2f(u1.x), s1.x, h1.x));
        a[5] = (_Float16)fast_tanh(fmaf(h2f(u1.y), s1.y, h1.y));
        a[6] = (_Float16)fast_tanh(fmaf(h2f(u1.z), s1.z, h1.z));
        a[7] = (_Float16)fast_tanh(fmaf(h2f(u1.w), s1.w, h1.w));
        af[kk] = a;
    }

    float* Cf = (float*)Av;
    for (int g = 0; g < 4; ++g) {
        {   // stage B group (conflict-free mapping)
            const float4* s4 = (const float4*)(Bf + (size_t)g * 16384);
#pragma unroll
            for (int i = 0; i < 8; ++i) lds4[i * 256 + t] = s4[i * 256 + t];
        }
        __syncthreads();  // also drains A-loads before in-place stores below

        f32x4 acc[4];
#pragma unroll
        for (int tg = 0; tg < 4; ++tg) acc[tg] = (f32x4){0.f, 0.f, 0.f, 0.f};

#pragma unroll
        for (int tg = 0; tg < 4; ++tg)
#pragma unroll
            for (int kk = 0; kk < 8; ++kk) {
                f16x8 b = *(const f16x8*)(lds + ((tg * 8 + kk) * 64 + lane) * 8);
                acc[tg] = __builtin_amdgcn_mfma_f32_16x16x32_f16(af[kk], b, acc[tg], 0, 0, 0);
            }
        __syncthreads();  // all waves done reading B before epilogue reuses lds

        // epilogue: acc -> LDS (wave-local 4KB f32 region) -> 16B NT stores
        {
            float* cw = (float*)lds4 + w * 1024;
#pragma unroll
            for (int tg = 0; tg < 4; ++tg)
#pragma unroll
                for (int j = 0; j < 4; ++j)
                    cw[(q * 4 + j) * 64 + tg * 16 + l] = acc[tg][j];
        }
        __syncthreads();
        {
            int gcol0 = g * 64;
#pragma unroll
            for (int p = 0; p < 4; ++p) {
                f32x4 rd = *(const f32x4*)((float*)lds4 + w * 1024 + p * 256 + lane * 4);
                int row = r0 + p * 4 + (lane >> 4);
                int col = gcol0 + (lane & 15) * 4;
                if (row < N)
                    __builtin_nontemporal_store(rd, (f32x4*)(Cf + (size_t)row * 256 + col));
            }
        }
        __syncthreads();
    }
}

extern "C" void kernel_launch(void* const* d_in, const int* in_sizes, int n_in,
                              void* d_out, int out_size, void* d_ws, size_t ws_size,
                              hipStream_t stream) {
    const float* x     = (const float*)d_in[0];
    const int* rows    = (const int*)d_in[1];
    const int* cols    = (const int*)d_in[2];
    const float* evin  = (const float*)d_in[3];
    const float* w1    = (const float*)d_in[4];
    const float* w2    = (const float*)d_in[5];
    const float* gamma = (const float*)d_in[6];
    const float* beta  = (const float*)d_in[7];
    float* out = (float*)d_out;

    const int N = in_sizes[0] / FDIM;       // 100000
    const int E = in_sizes[1];              // 1600000
    const int NB = (N + 511) >> 9;          // 196 coarse buckets
    const int nchunk = (E + CH - 1) / CH;   // 782

    char* ws = (char*)d_ws;
    size_t o = 0;
    auto alloc = [&](size_t bytes) -> char* {
        char* p = ws + o;
        o += (bytes + 255) & ~(size_t)255;
        return p;
    };
    ushort* h1f  = (ushort*)alloc(128 * 64 * 8 * 2);
    ushort* h2f  = (ushort*)alloc(128 * 64 * 8 * 2);
    ushort* y    = (ushort*)alloc((size_t)N * 256 * 2);             // 51.2 MB
    float* statsR = (float*)alloc(2 * NREP * 256 * 4);              // 64 KB
    int*   CM    = (int*)alloc((size_t)NB * nchunk * 4);            // 612 KB
    int*   PO    = (int*)alloc((size_t)NB * nchunk * 4);            // 612 KB
    int*   BT    = (int*)alloc(256 * 4);
    uint2* tmp2  = (uint2*)alloc((size_t)E * 8);                    // 12.8 MB
    unsigned int* ewp = (unsigned int*)alloc(((size_t)E + (size_t)NB * 4096 + 16) * 4);
    uint2* offs2 = (uint2*)alloc((size_t)N * 8);                    // 800 KB

    // init + p1 in one dispatch
    k_initp1<<<80 + nchunk, 256, 0, stream>>>(w1, w2, h1f, h2f, statsR,
                                              rows, CM, E, nchunk, NB);
    k_p2<<<NB, 256, 0, stream>>>(CM, PO, BT, nchunk);
    k_p3<<<nchunk, 256, 0, stream>>>(rows, cols, evin, PO, BT, tmp2, E, nchunk, NB);
    k_p4<<<NB, 1024, 0, stream>>>(tmp2, BT, ewp, offs2, N, NB);

    int gblk = (N + 63) / 64;  // 1563
    // y = x @ H1 (f16)
    k_gemm1<<<gblk, 256, 0, stream>>>(x, h1f, y, N);
    // out1(f16, interleaved in d_out) = segsum(ev*y[col]) + BN stats
    // XCD-partitioned: 8 slots x ceil(nRB/4) row-block groups
    int nRB = (N + 15) / 16;           // 6250 row-blocks of 16 rows
    int nRBG = (nRB + 3) / 4;          // 1563 groups of 4 stripes
    k_spmm<<<nRBG * 8, 256, 0, stream>>>(y, offs2, ewp, (ushort*)out, statsR, N);
    // d_out(f32) = tanh(BN(out1)) @ H2
    k_gemm2<<<gblk, 256, 0, stream>>>(out, h2f, statsR, gamma, beta, N);
}